// Round 1
// baseline (166.616 us; speedup 1.0000x reference)
//
#include <hip/hip_runtime.h>
#include <cmath>
#include <complex>

#define T_LEN   131072
#define B_ROWS  96
#define CHUNK   128                       // output samples per thread
#define WARM    128                       // warm-up samples (|p|max^128 ~ 6e-8)
#define NCHUNK  (T_LEN / CHUNK)           // 1024 chunks per row
#define TOTAL_THREADS (B_ROWS * NCHUNK)   // 98304
#define BLOCK   256

struct Coefs {
  float b0, b1, b2, b3, b4, b5, b6;
  float a1, a2, a3, a4, a5, a6;
  float invN;
};

// One DF2T step, matching the reference update:
//   y      = b0*x + z0
//   z_i    = z_{i+1} + b_{i+1}*x - a_{i+1}*y   (z_6 == 0)
#define LP_STEP(x, ACC)                                  \
  {                                                      \
    float y = fmaf(cf.b0, (x), z0);                      \
    ACC;                                                 \
    z0 = fmaf(-cf.a1, y, fmaf(cf.b1, (x), z1));          \
    z1 = fmaf(-cf.a2, y, fmaf(cf.b2, (x), z2));          \
    z2 = fmaf(-cf.a3, y, fmaf(cf.b3, (x), z3));          \
    z3 = fmaf(-cf.a4, y, fmaf(cf.b4, (x), z4));          \
    z4 = fmaf(-cf.a5, y, fmaf(cf.b5, (x), z5));          \
    z5 = fmaf(-cf.a6, y, cf.b6 * (x));                   \
  }

__global__ __launch_bounds__(BLOCK) void lp_mae_kernel(
    const float* __restrict__ out_p, const float* __restrict__ tgt_p,
    float* __restrict__ dout, Coefs cf)
{
  const int tid = blockIdx.x * BLOCK + threadIdx.x;
  const int row = tid >> 10;              // tid / NCHUNK
  const int c   = tid & (NCHUNK - 1);     // chunk index within row

  const int start  = c * CHUNK;
  const int wstart = (c == 0) ? 0 : (start - WARM);
  const int warm4  = (start - wstart) >> 2;   // 0 or WARM/4

  const size_t base = (size_t)row * T_LEN + (size_t)wstart;
  const float4* po = (const float4*)(out_p + base);
  const float4* pt = (const float4*)(tgt_p + base);

  float z0 = 0.f, z1 = 0.f, z2 = 0.f, z3 = 0.f, z4 = 0.f, z5 = 0.f;
  float sum = 0.f;

  // Warm-up: run the filter, discard outputs (c==0 skips this: exact zero init).
  for (int i = 0; i < warm4; ++i) {
    float4 xo = po[i];
    float4 xt = pt[i];
    LP_STEP(xo.x - xt.x, );
    LP_STEP(xo.y - xt.y, );
    LP_STEP(xo.z - xt.z, );
    LP_STEP(xo.w - xt.w, );
  }
  po += warm4;
  pt += warm4;

  // Main: filter + accumulate |y| over this thread's CHUNK samples.
  for (int i = 0; i < CHUNK / 4; ++i) {
    float4 xo = po[i];
    float4 xt = pt[i];
    LP_STEP(xo.x - xt.x, sum += fabsf(y));
    LP_STEP(xo.y - xt.y, sum += fabsf(y));
    LP_STEP(xo.z - xt.z, sum += fabsf(y));
    LP_STEP(xo.w - xt.w, sum += fabsf(y));
  }

  // Wave64 reduction, then one atomic per wave.
  #pragma unroll
  for (int off = 32; off > 0; off >>= 1)
    sum += __shfl_down(sum, off);
  if ((threadIdx.x & 63) == 0)
    atomicAdd(dout, sum * cf.invN);
}

extern "C" void kernel_launch(void* const* d_in, const int* in_sizes, int n_in,
                              void* d_out, int out_size, void* d_ws, size_t ws_size,
                              hipStream_t stream) {
  (void)in_sizes; (void)n_in; (void)d_ws; (void)ws_size; (void)out_size;

  const float* out_p = (const float*)d_in[0];
  const float* tgt_p = (const float*)d_in[1];
  float* dout = (float*)d_out;

  // ---- Host-side coefficient computation (mirrors _butter_lowpass in f64,
  // then casts to f32 exactly like the reference's .astype(np.float32)). ----
  using cd = std::complex<double>;
  const int order = 6;
  const double wn = 4000.0 / 24000.0;          // CUTOFF / (0.5 * SAMPLE_RATE)
  const double fs = 2.0;
  const double warped = 2.0 * fs * std::tan(M_PI * wn / fs);

  cd p[6];
  for (int k = 0; k < order; ++k) {
    int m = -order + 1 + 2 * k;                // [-5,-3,-1,1,3,5]
    p[k] = -std::exp(cd(0.0, M_PI * m / (2.0 * order))) * warped;
  }
  double kgain = std::pow(warped, (double)order);
  const double fs2 = 2.0 * fs;

  cd pz[6];
  cd prodden(1.0, 0.0);
  for (int k = 0; k < order; ++k) {
    pz[k] = (fs2 + p[k]) / (fs2 - p[k]);
    prodden *= (fs2 - p[k]);
  }
  double kz = kgain * std::real(1.0 / prodden);

  // b = kz * poly(-ones(6)) = kz * binomial(6, i)
  const double binom[7] = {1, 6, 15, 20, 15, 6, 1};
  double bd[7];
  for (int i = 0; i < 7; ++i) bd[i] = kz * binom[i];

  // a = real(poly(pz))
  cd ac[7];
  ac[0] = cd(1.0, 0.0);
  for (int i = 1; i < 7; ++i) ac[i] = cd(0.0, 0.0);
  for (int k = 0; k < order; ++k)
    for (int i = k + 1; i >= 1; --i)
      ac[i] = ac[i] - pz[k] * ac[i - 1];

  Coefs cf;
  cf.b0 = (float)bd[0]; cf.b1 = (float)bd[1]; cf.b2 = (float)bd[2];
  cf.b3 = (float)bd[3]; cf.b4 = (float)bd[4]; cf.b5 = (float)bd[5];
  cf.b6 = (float)bd[6];
  cf.a1 = (float)std::real(ac[1]); cf.a2 = (float)std::real(ac[2]);
  cf.a3 = (float)std::real(ac[3]); cf.a4 = (float)std::real(ac[4]);
  cf.a5 = (float)std::real(ac[5]); cf.a6 = (float)std::real(ac[6]);
  cf.invN = 1.0f / (float)((double)B_ROWS * (double)T_LEN);

  hipMemsetAsync(d_out, 0, sizeof(float), stream);
  lp_mae_kernel<<<TOTAL_THREADS / BLOCK, BLOCK, 0, stream>>>(out_p, tgt_p, dout, cf);
}